// Round 5
// baseline (727.830 us; speedup 1.0000x reference)
//
#include <hip/hip_runtime.h>
#include <math.h>

namespace {
constexpr int DIN = 36, DOUT = 34, BATCH = 8;
// output tile per block: (d,e,f) = (2,4,8) -> 64 outputs x 2 lanes (c-split) = 128 threads
constexpr int TD = 2, TE = 4, TF = 8;
constexpr int NBD = 17, NBE = 9, NBF = 5;            // 17*2=34 exact, 9*4=36, 5*8=40
constexpr int BLOCKS_PER_B = NBD * NBE * NBF;        // 765
constexpr int NBLOCKS = BATCH * BLOCKS_PER_B;        // 6120 = 8 XCDs x 765
}

__global__ __launch_bounds__(128, 8)
void lasl_kernel(const float* __restrict__ xr, const float* __restrict__ xi,
                 const float* __restrict__ wr, const float* __restrict__ wi,
                 const float* __restrict__ br, const float* __restrict__ bi,
                 const float* __restrict__ hw, const float* __restrict__ hb,
                 float* __restrict__ out)
{
    __shared__ float4 s_wr4[27], s_wi4[27];          // [ijk] = {w_l0, w_l1, w_l2, 0}
    __shared__ float s_hw[DOUT], s_scal[3];
    const int t = threadIdx.x;
    if (t < 27) {
        s_wr4[t] = make_float4(wr[t*3], wr[t*3+1], wr[t*3+2], 0.f);
        s_wi4[t] = make_float4(wi[t*3], wi[t*3+1], wi[t*3+2], 0.f);
    } else if (t >= 32 && t < 32 + DOUT) {
        s_hw[t-32] = hw[t-32];
    } else if (t == 96) { s_scal[0] = br[0]; s_scal[1] = bi[0]; s_scal[2] = hb[0]; }
    __syncthreads();

    // Bijective XCD swizzle: 6120 = 8 * 765; XCD x owns batch x entirely.
    const int bid = blockIdx.x;
    const int b   = bid & 7;
    int rem = bid >> 3;                               // bd-major within batch
    const int bd = rem / (NBE*NBF); rem %= (NBE*NBF);
    const int be = rem / NBF;
    const int bf = rem % NBF;

    // lane bit0 = input channel c (0: real, 1: imag); pair shares one output
    const int c = t & 1;
    const int f = bf*TF + ((t>>1) & 7);
    const int e = be*TE + ((t>>4) & 3);
    const int d = bd*TD + ((t>>6) & 1);
    if (e >= DOUT || f >= DOUT) return;               // pair-uniform -> shfl-safe

    const float* __restrict__ xc = c ? xi : xr;
    const float* __restrict__ base =
        xc + ((((size_t)b*DIN + d)*DIN + e)*DIN + f) * DIN;

    const float c_br = s_scal[0], c_bi = s_scal[1];
    float h = s_scal[2];

    // 4 sequential w-passes (9,8,9,8) keep live set ~48 VGPR (8 waves/SIMD).
    #pragma unroll
    for (int p = 0; p < 4; ++p)
    {
        const int W0 = (p==0) ? 0 : (p==1) ? 9 : (p==2) ? 17 : 26;
        const int NW = (p==0 || p==2) ? 9 : 8;
        const int FB = p * 8;                         // float4-aligned window start
        const int SH = W0 - FB;                       // 0,1,1,2 (compile-time)

        float a[9], g[9];                             // a = sum v*wr, g = sum v*wi
        #pragma unroll
        for (int w = 0; w < 9; ++w) { a[w] = 0.f; g[w] = 0.f; }

        #pragma unroll 1
        for (int i = 0; i < 3; ++i)
        #pragma unroll 1
        for (int j = 0; j < 3; ++j)
        #pragma unroll 1
        for (int k = 0; k < 3; ++k)
        {
            const float* rp = base + (size_t)(i*(DIN*DIN) + j*DIN + k)*DIN + FB;
            float q[12];
            float4* q4 = reinterpret_cast<float4*>(q);
            const float4* src = reinterpret_cast<const float4*>(rp);
            q4[0] = src[0]; q4[1] = src[1]; q4[2] = src[2];

            const int ijk = (i*3 + j)*3 + k;
            const float4 wv_r = s_wr4[ijk];           // uniform -> LDS broadcast
            const float4 wv_i = s_wi4[ijk];
            #pragma unroll
            for (int l = 0; l < 3; ++l) {
                const float wrl = (l==0) ? wv_r.x : (l==1) ? wv_r.y : wv_r.z;
                const float wil = (l==0) ? wv_i.x : (l==1) ? wv_i.y : wv_i.z;
                #pragma unroll
                for (int w = 0; w < NW; ++w) {
                    const float v = q[w + l + SH];    // compile-time index
                    a[w] = fmaf(v, wrl, a[w]);
                    g[w] = fmaf(v, wil, g[w]);
                }
            }
        }

        // combine lane pair: lane0 holds (A0,B0)=(sum xr*wr, sum xr*wi),
        // lane1 holds (A1,B1)=(sum xi*wr, sum xi*wi).
        // yr = A0 - B1 + br ; yi = B0 + A1 + bi  (identical on both lanes)
        #pragma unroll
        for (int w = 0; w < NW; ++w) {
            const float pa = __shfl_xor(a[w], 1);
            const float pg = __shfl_xor(g[w], 1);
            float yr = c ? (pa - g[w]) : (a[w] - pg);
            float yi = c ? (pg + a[w]) : (g[w] + pa);
            yr = fmaxf(yr + c_br, 0.f);
            yi = fmaxf(yi + c_bi, 0.f);
            const float m = sqrtf(fmaf(yr, yr, fmaf(yi, yi, 1e-12f)));
            h = fmaf(m, s_hw[W0 + w], h);
        }
    }

    if (!c)
        out[(((size_t)b*DOUT + d)*DOUT + e)*DOUT + f] = 1.0f / (1.0f + __expf(-h));
}

extern "C" void kernel_launch(void* const* d_in, const int* in_sizes, int n_in,
                              void* d_out, int out_size, void* d_ws, size_t ws_size,
                              hipStream_t stream)
{
    const float* xr = (const float*)d_in[0];
    const float* xi = (const float*)d_in[1];
    const float* wr = (const float*)d_in[2];
    const float* wi = (const float*)d_in[3];
    const float* br = (const float*)d_in[4];
    const float* bi = (const float*)d_in[5];
    const float* hw = (const float*)d_in[6];
    const float* hb = (const float*)d_in[7];
    float* out = (float*)d_out;

    lasl_kernel<<<NBLOCKS, 128, 0, stream>>>(xr, xi, wr, wi, br, bi, hw, hb, out);
}

// Round 6
// 190.444 us; speedup vs baseline: 3.8218x; 3.8218x over previous
//
#include <hip/hip_runtime.h>
#include <math.h>

namespace {
constexpr int DIN = 36, DOUT = 34;
constexpr int TDD = 2, TE = 8, TF = 8;          // output tile (d,e,f) per block
constexpr int RD = TDD+2, RE = TE+2, RF = TF+2; // staged region rows: 4 x 10 x 10
constexpr int NROWS = RD*RE*RF;                 // 400 rows of 36 floats
constexpr int CHUNKS = NROWS*9;                 // 3600 float4 chunks = 57.6 KB
constexpr int NBD = 17, NBE = 5, NBF = 5;       // 17*2=34 exact; 5*8=40 covers 34
constexpr int BLOCKS_PER_B = NBD*NBE*NBF;       // 425
constexpr int NBLOCKS = 8*BLOCKS_PER_B;         // 3400 = 8 XCDs x 425
constexpr int NT = 256;
constexpr int STAGE_ITERS = (CHUNKS + NT - 1)/NT;  // 15
}

__device__ __forceinline__ unsigned div9u(unsigned n)   { return __umulhi(n, 0x38E38E39u) >> 1; }
__device__ __forceinline__ unsigned div100u(unsigned n) { return __umulhi(n, 0x51EB851Fu) >> 5; }
__device__ __forceinline__ unsigned div10u(unsigned n)  { return __umulhi(n, 0x66666667u) >> 2; }

// Coalesced stage of the block's input region (one channel) into LDS.
// Chunk C -> row C/9, chunk-in-row C%9; 9 consecutive lanes read 144B contiguous.
// LDS dest is linear (chunk C at offset 16C) -> conflict-free ds_write.
__device__ __forceinline__ void stage(const float* __restrict__ xg, float4* __restrict__ s_x,
                                      int t, int d0, int e0, int f0)
{
    #pragma unroll 5
    for (int it = 0; it < STAGE_ITERS; ++it) {
        const int C = it*NT + t;
        if (C < CHUNKS) {
            const unsigned row = div9u((unsigned)C);
            const unsigned c   = (unsigned)C - row*9u;
            const unsigned rd  = div100u(row);
            const unsigned rem = row - rd*100u;
            const unsigned re  = div10u(rem);
            const unsigned rf  = rem - re*10u;
            const int ee = min((int)(e0+re), 35);   // clamp: tail rows, consumed only by
            const int ff = min((int)(f0+rf), 35);   // inactive threads
            const size_t goff = (((size_t)(d0+rd)*DIN + ee)*DIN + ff)*DIN + c*4;
            s_x[C] = *reinterpret_cast<const float4*>(xg + goff);
        }
    }
}

// One channel's conv accumulation from LDS. h is wave-uniform; NW/QOFF/IDXOFF are
// compile-time so all register-buffer indices are constant (no scratch demotion).
// h=0: w 0..17 reads floats [0,20); h=1: w 18..33 reads floats [16,36).
template<int NW, int QOFF, int IDXOFF, bool IMAG>
__device__ __forceinline__ void conv_pass(const float4* __restrict__ s_x,
                                          const float4* __restrict__ s_wr4,
                                          const float4* __restrict__ s_wi4,
                                          int td, int e, int f,
                                          float (&yr)[18], float (&yi)[18])
{
    #pragma unroll 1
    for (int i = 0; i < 3; ++i)
    #pragma unroll 1
    for (int j = 0; j < 3; ++j)
    #pragma unroll 1
    for (int k = 0; k < 3; ++k)
    {
        const int r = (td+i)*(RE*RF) + (e+j)*RF + (f+k);
        const float4* src = s_x + r*9 + QOFF;
        float4 q4[5];
        #pragma unroll
        for (int q = 0; q < 5; ++q) q4[q] = src[q];
        const float* qf = reinterpret_cast<const float*>(q4);

        const int ijk = (i*3 + j)*3 + k;
        const float4 w_r = s_wr4[ijk];               // broadcast LDS reads
        const float4 w_i = s_wi4[ijk];
        #pragma unroll
        for (int l = 0; l < 3; ++l) {
            const float wrl = (l==0) ? w_r.x : (l==1) ? w_r.y : w_r.z;
            const float wil = (l==0) ? w_i.x : (l==1) ? w_i.y : w_i.z;
            const float cr = IMAG ? -wil : wrl;      // yr += v*cr
            const float ci = IMAG ?  wrl : wil;      // yi += v*ci
            #pragma unroll
            for (int w = 0; w < NW; ++w) {
                const float v = qf[w + l + IDXOFF];  // compile-time index
                yr[w] = fmaf(v, cr, yr[w]);
                yi[w] = fmaf(v, ci, yi[w]);
            }
        }
    }
}

template<int NW, int W0>
__device__ __forceinline__ float epilogue(const float (&yr)[18], const float (&yi)[18],
                                          const float* __restrict__ s_hw, float hacc)
{
    #pragma unroll
    for (int w = 0; w < NW; ++w) {
        const float a = fmaxf(yr[w], 0.f);
        const float c = fmaxf(yi[w], 0.f);
        const float m = sqrtf(fmaf(a, a, fmaf(c, c, 1e-12f)));
        hacc = fmaf(m, s_hw[W0 + w], hacc);
    }
    return hacc;
}

__global__ __launch_bounds__(NT)
void lasl_kernel(const float* __restrict__ xr, const float* __restrict__ xi,
                 const float* __restrict__ wr, const float* __restrict__ wi,
                 const float* __restrict__ br, const float* __restrict__ bi,
                 const float* __restrict__ hw, const float* __restrict__ hb,
                 float* __restrict__ out)
{
    __shared__ float4 s_x[CHUNKS];                   // 57.6 KB staging tile
    __shared__ float4 s_wr4[27], s_wi4[27];
    __shared__ float s_hw[DOUT], s_scal[3];

    const int t = threadIdx.x;
    if (t < 27) {
        s_wr4[t] = make_float4(wr[3*t], wr[3*t+1], wr[3*t+2], 0.f);
        s_wi4[t] = make_float4(wi[3*t], wi[3*t+1], wi[3*t+2], 0.f);
    } else if (t >= 32 && t < 32 + DOUT) {
        s_hw[t-32] = hw[t-32];
    } else if (t == 96) { s_scal[0] = br[0]; s_scal[1] = bi[0]; s_scal[2] = hb[0]; }

    // batch-per-XCD bijective swizzle: 3400 = 8 * 425
    const int bid = blockIdx.x;
    const int b   = bid & 7;
    int rem = bid >> 3;                              // 0..424
    const int bd = rem / 25;  rem %= 25;
    const int be = rem / 5;
    const int bf = rem % 5;
    const int d0 = bd*TDD, e0 = be*TE, f0 = bf*TF;

    const int f  = t & 7;                            // lane: f(8) x e(8)
    const int e  = (t >> 3) & 7;
    const int h  = (t >> 6) & 1;                     // wave-uniform w-half
    const int td = (t >> 7) & 1;                     // wave-uniform d-sub

    const int dg = d0 + td;                          // always < 34 (17*2 exact)
    const int eg = e0 + e, fg = f0 + f;
    const bool act = (eg < DOUT) & (fg < DOUT);

    const size_t bstride = (size_t)DIN*DIN*DIN*DIN;
    const float* xrb = xr + (size_t)b * bstride;
    const float* xib = xi + (size_t)b * bstride;

    // ---- pass A: real channel
    stage(xrb, s_x, t, d0, e0, f0);
    __syncthreads();

    const float c_br = s_scal[0], c_bi = s_scal[1];
    float yr[18], yi[18];
    #pragma unroll
    for (int w = 0; w < 18; ++w) { yr[w] = c_br; yi[w] = c_bi; }

    if (act) {
        if (h == 0) conv_pass<18,0,0,false>(s_x, s_wr4, s_wi4, td, e, f, yr, yi);
        else        conv_pass<16,4,2,false>(s_x, s_wr4, s_wi4, td, e, f, yr, yi);
    }
    __syncthreads();                                 // all s_x reads done

    // ---- pass B: imag channel
    stage(xib, s_x, t, d0, e0, f0);
    __syncthreads();
    if (act) {
        if (h == 0) conv_pass<18,0,0,true>(s_x, s_wr4, s_wi4, td, e, f, yr, yi);
        else        conv_pass<16,4,2,true>(s_x, s_wr4, s_wi4, td, e, f, yr, yi);
    }

    // ---- CReLU -> modulus -> head partial (hb counted once, on h=0)
    float hacc = (h == 0) ? s_scal[2] : 0.f;
    if (act) {
        if (h == 0) hacc = epilogue<18,0>(yr, yi, s_hw, hacc);
        else        hacc = epilogue<16,18>(yr, yi, s_hw, hacc);
    }

    // ---- combine the two w-halves (different waves) through LDS
    __syncthreads();                                 // safe to reuse s_x
    float* s_red = reinterpret_cast<float*>(s_x);
    s_red[t] = hacc;
    __syncthreads();
    if (h == 0 && act) {
        const float tot = hacc + s_red[t + 64];
        out[(((size_t)b*DOUT + dg)*DOUT + eg)*DOUT + fg] = 1.f / (1.f + __expf(-tot));
    }
}

extern "C" void kernel_launch(void* const* d_in, const int* in_sizes, int n_in,
                              void* d_out, int out_size, void* d_ws, size_t ws_size,
                              hipStream_t stream)
{
    const float* xr = (const float*)d_in[0];
    const float* xi = (const float*)d_in[1];
    const float* wr = (const float*)d_in[2];
    const float* wi = (const float*)d_in[3];
    const float* br = (const float*)d_in[4];
    const float* bi = (const float*)d_in[5];
    const float* hw = (const float*)d_in[6];
    const float* hb = (const float*)d_in[7];
    float* out = (float*)d_out;

    lasl_kernel<<<NBLOCKS, NT, 0, stream>>>(xr, xi, wr, wi, br, bi, hw, hb, out);
}

// Round 7
// 184.910 us; speedup vs baseline: 3.9361x; 1.0299x over previous
//
#include <hip/hip_runtime.h>
#include <hip/hip_fp16.h>
#include <math.h>

namespace {
constexpr int DIN = 36, DOUT = 34;
constexpr int TDD = 2, TE = 8, TF = 8;          // output tile (d,e,f) per block
constexpr int RD = TDD+2, RE = TE+2, RF = TF+2; // staged region: 4 x 10 x 10 rows
constexpr int NROWS = RD*RE*RF;                 // 400 rows
constexpr int ROWH  = 40;                       // halves per row (36 + 4 pad) = 80 B
constexpr int SCHUNKS = NROWS*9;                // 3600 f32 source chunks (4 floats each)
constexpr int NBD = 17, NBE = 5, NBF = 5;
constexpr int BLOCKS_PER_B = NBD*NBE*NBF;       // 425
constexpr int NBLOCKS = 8*BLOCKS_PER_B;         // 3400 = 8 XCDs x 425
constexpr int NT = 256;
constexpr int STAGE_ITERS = (SCHUNKS + NT - 1)/NT;  // 15
}

__device__ __forceinline__ unsigned div9u(unsigned n)   { return __umulhi(n, 0x38E38E39u) >> 1; }
__device__ __forceinline__ unsigned div100u(unsigned n) { return __umulhi(n, 0x51EB851Fu) >> 5; }
__device__ __forceinline__ unsigned div10u(unsigned n)  { return __umulhi(n, 0x66666667u) >> 2; }

// Coalesced stage (9 consecutive lanes read one 144B row contiguously), f32 -> fp16.
// Chunk C: row C/9, 4 floats at float-offset (C%9)*4; LDS dest 8B at row*80 + c*8.
__device__ __forceinline__ void stage(const float* __restrict__ xg, __half* __restrict__ s_x,
                                      int t, int d0, int e0, int f0)
{
    #pragma unroll 5
    for (int it = 0; it < STAGE_ITERS; ++it) {
        const int C = it*NT + t;
        if (C < SCHUNKS) {
            const unsigned row = div9u((unsigned)C);
            const unsigned c   = (unsigned)C - row*9u;
            const unsigned rd  = div100u(row);
            const unsigned rem = row - rd*100u;
            const unsigned re  = div10u(rem);
            const unsigned rf  = rem - re*10u;
            const int ee = min((int)(e0+re), 35);   // clamped tail rows: only read by
            const int ff = min((int)(f0+rf), 35);   // inactive (masked) threads
            const size_t goff = (((size_t)(d0+rd)*DIN + ee)*DIN + ff)*DIN + c*4;
            const float4 v = *reinterpret_cast<const float4*>(xg + goff);
            union { __half2 h2[2]; float2 f2; } u;
            u.h2[0] = __floats2half2_rn(v.x, v.y);
            u.h2[1] = __floats2half2_rn(v.z, v.w);
            *reinterpret_cast<float2*>(s_x + row*ROWH + c*4) = u.f2;   // 8B store
        }
    }
}

// One channel's conv from fp16 LDS. h wave-uniform; all reg indices compile-time.
// h=0 (NW=18): chunks 0..2 (halves 0..23), uses idx 0..19.
// h=1 (NW=16): chunks 2..4 (halves 16..39), uses rel idx 2..19 (halves 18..35).
template<int NW, int QOFF, int IDXOFF, bool IMAG>
__device__ __forceinline__ void conv_pass(const __half* __restrict__ s_x,
                                          const float4* __restrict__ s_wr4,
                                          const float4* __restrict__ s_wi4,
                                          int td, int e, int f,
                                          float (&yr)[18], float (&yi)[18])
{
    #pragma unroll 1
    for (int i = 0; i < 3; ++i)
    #pragma unroll 1
    for (int j = 0; j < 3; ++j)
    #pragma unroll 1
    for (int k = 0; k < 3; ++k)
    {
        const int r = (td+i)*(RE*RF) + (e+j)*RF + (f+k);
        const float4* sp = reinterpret_cast<const float4*>(s_x + r*ROWH + QOFF*8);
        float4 q4[3];
        #pragma unroll
        for (int q = 0; q < 3; ++q) q4[q] = sp[q];   // 3 x ds_read_b128
        const __half* hh = reinterpret_cast<const __half*>(q4);

        float v[20];
        #pragma unroll
        for (int m = 0; m < NW+2; ++m) v[m] = __half2float(hh[IDXOFF + m]);

        const int ijk = (i*3 + j)*3 + k;
        const float4 w_r = s_wr4[ijk];               // uniform broadcast reads
        const float4 w_i = s_wi4[ijk];
        #pragma unroll
        for (int l = 0; l < 3; ++l) {
            const float wrl = (l==0) ? w_r.x : (l==1) ? w_r.y : w_r.z;
            const float wil = (l==0) ? w_i.x : (l==1) ? w_i.y : w_i.z;
            const float cr = IMAG ? -wil : wrl;
            const float ci = IMAG ?  wrl : wil;
            #pragma unroll
            for (int w = 0; w < NW; ++w) {
                yr[w] = fmaf(v[w+l], cr, yr[w]);
                yi[w] = fmaf(v[w+l], ci, yi[w]);
            }
        }
    }
}

template<int NW, int W0>
__device__ __forceinline__ float epilogue(const float (&yr)[18], const float (&yi)[18],
                                          const float* __restrict__ s_hw, float hacc)
{
    #pragma unroll
    for (int w = 0; w < NW; ++w) {
        const float a = fmaxf(yr[w], 0.f);
        const float c = fmaxf(yi[w], 0.f);
        const float m = sqrtf(fmaf(a, a, fmaf(c, c, 1e-12f)));
        hacc = fmaf(m, s_hw[W0 + w], hacc);
    }
    return hacc;
}

__global__ __launch_bounds__(NT)
void lasl_kernel(const float* __restrict__ xr, const float* __restrict__ xi,
                 const float* __restrict__ wr, const float* __restrict__ wi,
                 const float* __restrict__ br, const float* __restrict__ bi,
                 const float* __restrict__ hw, const float* __restrict__ hb,
                 float* __restrict__ out)
{
    __shared__ __half s_x[NROWS*ROWH];              // 32 KB fp16 staging tile
    __shared__ float4 s_wr4[27], s_wi4[27];         // weights stay fp32
    __shared__ float s_hw[DOUT], s_scal[3];

    const int t = threadIdx.x;
    if (t < 27) {
        s_wr4[t] = make_float4(wr[3*t], wr[3*t+1], wr[3*t+2], 0.f);
        s_wi4[t] = make_float4(wi[3*t], wi[3*t+1], wi[3*t+2], 0.f);
    } else if (t >= 32 && t < 32 + DOUT) {
        s_hw[t-32] = hw[t-32];
    } else if (t == 96) { s_scal[0] = br[0]; s_scal[1] = bi[0]; s_scal[2] = hb[0]; }

    // batch-per-XCD bijective swizzle: 3400 = 8 * 425
    const int bid = blockIdx.x;
    const int b   = bid & 7;
    int rem = bid >> 3;
    const int bd = rem / 25;  rem %= 25;
    const int be = rem / 5;
    const int bf = rem % 5;
    const int d0 = bd*TDD, e0 = be*TE, f0 = bf*TF;

    const int f  = t & 7;
    const int e  = (t >> 3) & 7;
    const int h  = (t >> 6) & 1;                    // wave-uniform w-half
    const int td = (t >> 7) & 1;                    // wave-uniform d-sub

    const int dg = d0 + td;
    const int eg = e0 + e, fg = f0 + f;
    const bool act = (eg < DOUT) & (fg < DOUT);

    const size_t bstride = (size_t)DIN*DIN*DIN*DIN;
    const float* xrb = xr + (size_t)b * bstride;
    const float* xib = xi + (size_t)b * bstride;

    // ---- pass A: real channel
    stage(xrb, s_x, t, d0, e0, f0);
    __syncthreads();

    const float c_br = s_scal[0], c_bi = s_scal[1];
    float yr[18], yi[18];
    #pragma unroll
    for (int w = 0; w < 18; ++w) { yr[w] = c_br; yi[w] = c_bi; }

    if (act) {
        if (h == 0) conv_pass<18,0,0,false>(s_x, s_wr4, s_wi4, td, e, f, yr, yi);
        else        conv_pass<16,2,2,false>(s_x, s_wr4, s_wi4, td, e, f, yr, yi);
    }
    __syncthreads();

    // ---- pass B: imag channel
    stage(xib, s_x, t, d0, e0, f0);
    __syncthreads();
    if (act) {
        if (h == 0) conv_pass<18,0,0,true>(s_x, s_wr4, s_wi4, td, e, f, yr, yi);
        else        conv_pass<16,2,2,true>(s_x, s_wr4, s_wi4, td, e, f, yr, yi);
    }

    // ---- CReLU -> modulus -> head partial (hb counted once, on h=0)
    float hacc = (h == 0) ? s_scal[2] : 0.f;
    if (act) {
        if (h == 0) hacc = epilogue<18,0>(yr, yi, s_hw, hacc);
        else        hacc = epilogue<16,18>(yr, yi, s_hw, hacc);
    }

    // ---- combine the two w-halves (different waves) through LDS
    __syncthreads();
    float* s_red = reinterpret_cast<float*>(s_x);
    s_red[t] = hacc;
    __syncthreads();
    if (h == 0 && act) {
        const float tot = hacc + s_red[t + 64];
        out[(((size_t)b*DOUT + dg)*DOUT + eg)*DOUT + fg] = 1.f / (1.f + __expf(-tot));
    }
}

extern "C" void kernel_launch(void* const* d_in, const int* in_sizes, int n_in,
                              void* d_out, int out_size, void* d_ws, size_t ws_size,
                              hipStream_t stream)
{
    const float* xr = (const float*)d_in[0];
    const float* xi = (const float*)d_in[1];
    const float* wr = (const float*)d_in[2];
    const float* wi = (const float*)d_in[3];
    const float* br = (const float*)d_in[4];
    const float* bi = (const float*)d_in[5];
    const float* hw = (const float*)d_in[6];
    const float* hb = (const float*)d_in[7];
    float* out = (float*)d_out;

    lasl_kernel<<<NBLOCKS, NT, 0, stream>>>(xr, xi, wr, wi, br, bi, hw, hb, out);
}

// Round 8
// 126.656 us; speedup vs baseline: 5.7465x; 1.4599x over previous
//
#include <hip/hip_runtime.h>
#include <math.h>

typedef _Float16 f16x2 __attribute__((ext_vector_type(2)));

namespace {
constexpr int DIN = 36, DOUT = 34;
constexpr int TE = 8, TF = 8;                   // site tile: (d,e,f) = (1,8,8)
constexpr int RE = TE+2, RF = TF+2;             // staged region: 3 x 10 x 10 rows
constexpr int NROWS = 3*RE*RF;                  // 300 rows
constexpr int ROWB  = 144;                      // 36 half2 per row = 144 B (36 banks = 4 mod 32)
constexpr int NCHUNK = NROWS*9;                 // 2700 16B chunks
constexpr int NBD = 34, NBE = 5, NBF = 5;
constexpr int BLOCKS_PER_B = NBD*NBE*NBF;       // 850
constexpr int NBLOCKS = 8*BLOCKS_PER_B;         // 6800 = 8 XCDs x 850
constexpr int NT = 512;
constexpr int SITER = (NCHUNK + NT - 1)/NT;     // 6
}

__device__ __forceinline__ unsigned div9u(unsigned n)   { return __umulhi(n, 0x38E38E39u) >> 1; }
__device__ __forceinline__ unsigned div100u(unsigned n) { return __umulhi(n, 0x51EB851Fu) >> 5; }
__device__ __forceinline__ unsigned div10u(unsigned n)  { return __umulhi(n, 0x66666667u) >> 2; }

__device__ __forceinline__ float h2f(f16x2 h) { union { f16x2 h; float f; } u; u.h = h; return u.f; }
__device__ __forceinline__ f16x2 f2h(float f) { union { float f; f16x2 h; } u; u.f = f; return u.h; }

#if __has_builtin(__builtin_amdgcn_fdot2)
__device__ __forceinline__ float dot2(f16x2 a, f16x2 b, float c) {
    return __builtin_amdgcn_fdot2(a, b, c, false);
}
#else
__device__ __forceinline__ float dot2(f16x2 a, f16x2 b, float c) {
    return fmaf((float)a.x, (float)b.x, fmaf((float)a.y, (float)b.y, c));
}
#endif

// Coalesced stage of BOTH channels, interleaved (xr,xi) as half2. Chunk C:
// row C/9, 4 half2 at chunk C%9. LDS linear by C -> contiguous, conflict-free writes.
__device__ __forceinline__ void stage(const float* __restrict__ xr, const float* __restrict__ xi,
                                      char* __restrict__ s_x, int t, int d0, int e0, int f0)
{
    #pragma unroll
    for (int it = 0; it < SITER; ++it) {
        const int C = it*NT + t;
        if (C < NCHUNK) {
            const unsigned row = div9u((unsigned)C);
            const unsigned c   = (unsigned)C - row*9u;
            const unsigned rd  = div100u(row);
            const unsigned rem = row - rd*100u;
            const unsigned re  = div10u(rem);
            const unsigned rf  = rem - re*10u;
            const int ee = min((int)(e0+re), 35);     // clamped tail rows are read
            const int ff = min((int)(f0+rf), 35);     // only by inactive sites
            const size_t goff = (((size_t)(d0+rd)*DIN + ee)*DIN + ff)*DIN + c*4;
            const float4 vr = *reinterpret_cast<const float4*>(xr + goff);
            const float4 vi = *reinterpret_cast<const float4*>(xi + goff);
            float4 pk;
            pk.x = h2f(f16x2{(_Float16)vr.x, (_Float16)vi.x});
            pk.y = h2f(f16x2{(_Float16)vr.y, (_Float16)vi.y});
            pk.z = h2f(f16x2{(_Float16)vr.z, (_Float16)vi.z});
            pk.w = h2f(f16x2{(_Float16)vr.w, (_Float16)vi.w});
            *reinterpret_cast<float4*>(s_x + (size_t)C*16) = pk;
        }
    }
}

// One w-group's full conv + epilogue. All register indices compile-time.
// CB = chunk base (2 chunks read), WL = half2 offset of w0 within buffer.
template<int NW, int CB, int WL, int W0>
__device__ __forceinline__ float conv_group(const char* __restrict__ s_x,
                                            const float4* __restrict__ s_wA,
                                            const float4* __restrict__ s_wB,
                                            int e, int f,
                                            const float* __restrict__ s_hw,
                                            float c_br, float c_bi, float hinit)
{
    float yr[NW], yi[NW];
    #pragma unroll
    for (int w = 0; w < NW; ++w) { yr[w] = c_br; yi[w] = c_bi; }

    #pragma unroll 1
    for (int i = 0; i < 3; ++i)
    #pragma unroll 1
    for (int j = 0; j < 3; ++j)
    #pragma unroll 1
    for (int k = 0; k < 3; ++k)
    {
        const int r = i*(RE*RF) + (e+j)*RF + (f+k);
        const float4* sp = reinterpret_cast<const float4*>(s_x + r*ROWB + CB*16);
        float4 q4[2];
        q4[0] = sp[0]; q4[1] = sp[1];                 // 2 x ds_read_b128
        const f16x2* q = reinterpret_cast<const f16x2*>(q4);

        const int tap = (i*3 + j)*3 + k;
        const float4 wa = s_wA[tap];                  // uniform broadcast reads
        const float4 wb = s_wB[tap];
        #pragma unroll
        for (int l = 0; l < 3; ++l) {
            const f16x2 wal = f2h(l==0 ? wa.x : l==1 ? wa.y : wa.z);  // (wr, -wi)
            const f16x2 wbl = f2h(l==0 ? wb.x : l==1 ? wb.y : wb.z);  // (wi,  wr)
            #pragma unroll
            for (int w = 0; w < NW; ++w) {
                const f16x2 x2 = q[WL + w + l];       // (xr, xi), compile-time idx
                yr[w] = dot2(x2, wal, yr[w]);
                yi[w] = dot2(x2, wbl, yi[w]);
            }
        }
    }

    float h = hinit;
    #pragma unroll
    for (int w = 0; w < NW; ++w) {
        const float a = fmaxf(yr[w], 0.f);
        const float c = fmaxf(yi[w], 0.f);
        const float m = sqrtf(fmaf(a, a, fmaf(c, c, 1e-12f)));
        h = fmaf(m, s_hw[W0 + w], h);
    }
    return h;
}

__global__ __launch_bounds__(NT)
void lasl_kernel(const float* __restrict__ xr, const float* __restrict__ xi,
                 const float* __restrict__ wr, const float* __restrict__ wi,
                 const float* __restrict__ br, const float* __restrict__ bi,
                 const float* __restrict__ hw, const float* __restrict__ hb,
                 float* __restrict__ out)
{
    __shared__ char   s_x[NROWS*ROWB];              // 43.2 KB interleaved fp16 tile
    __shared__ float4 s_wA[27], s_wB[27];           // packed half2 weights per tap
    __shared__ float  s_hw[DOUT], s_scal[3];

    const int t = threadIdx.x;
    if (t < 27) {
        const float w0r = wr[3*t], w1r = wr[3*t+1], w2r = wr[3*t+2];
        const float w0i = wi[3*t], w1i = wi[3*t+1], w2i = wi[3*t+2];
        s_wA[t] = make_float4(h2f(f16x2{(_Float16)w0r, (_Float16)(-w0i)}),
                              h2f(f16x2{(_Float16)w1r, (_Float16)(-w1i)}),
                              h2f(f16x2{(_Float16)w2r, (_Float16)(-w2i)}), 0.f);
        s_wB[t] = make_float4(h2f(f16x2{(_Float16)w0i, (_Float16)w0r}),
                              h2f(f16x2{(_Float16)w1i, (_Float16)w1r}),
                              h2f(f16x2{(_Float16)w2i, (_Float16)w2r}), 0.f);
    } else if (t >= 32 && t < 32 + DOUT) {
        s_hw[t-32] = hw[t-32];
    } else if (t == 96) { s_scal[0] = br[0]; s_scal[1] = bi[0]; s_scal[2] = hb[0]; }

    // batch-per-XCD bijective swizzle: 6800 = 8 * 850
    const int bid = blockIdx.x;
    const int b   = bid & 7;
    int rem = bid >> 3;                              // 0..849
    const int d0 = rem / 25;  rem %= 25;             // NBD = 34 (TDD = 1)
    const int e0 = (rem / 5) * TE;
    const int f0 = (rem % 5) * TF;

    const size_t bstride = (size_t)DIN*DIN*DIN*DIN;
    stage(xr + (size_t)b*bstride, xi + (size_t)b*bstride, s_x, t, d0, e0, f0);
    __syncthreads();

    const int f = t & 7;                             // site within tile
    const int e = (t >> 3) & 7;
    const int g = t >> 6;                            // wave-uniform w-group (8 waves)

    const float c_br = s_scal[0], c_bi = s_scal[1];
    const float hini = (g == 0) ? s_scal[2] : 0.f;   // hb counted once

    float hp;
    if      (g == 0) hp = conv_group<5,0,0, 0>(s_x, s_wA, s_wB, e, f, s_hw, c_br, c_bi, hini);
    else if (g == 1) hp = conv_group<5,1,1, 5>(s_x, s_wA, s_wB, e, f, s_hw, c_br, c_bi, hini);
    else if (g == 2) hp = conv_group<4,2,2,10>(s_x, s_wA, s_wB, e, f, s_hw, c_br, c_bi, hini);
    else if (g == 3) hp = conv_group<4,3,2,14>(s_x, s_wA, s_wB, e, f, s_hw, c_br, c_bi, hini);
    else if (g == 4) hp = conv_group<4,4,2,18>(s_x, s_wA, s_wB, e, f, s_hw, c_br, c_bi, hini);
    else if (g == 5) hp = conv_group<4,5,2,22>(s_x, s_wA, s_wB, e, f, s_hw, c_br, c_bi, hini);
    else if (g == 6) hp = conv_group<4,6,2,26>(s_x, s_wA, s_wB, e, f, s_hw, c_br, c_bi, hini);
    else             hp = conv_group<4,7,2,30>(s_x, s_wA, s_wB, e, f, s_hw, c_br, c_bi, hini);

    // combine the 8 w-group partials (one per wave) through LDS
    __syncthreads();                                 // all s_x reads done
    float* s_red = reinterpret_cast<float*>(s_x);
    s_red[t] = hp;
    __syncthreads();

    if (g == 0) {
        const int eg = e0 + e, fg = f0 + f;
        if (eg < DOUT && fg < DOUT) {
            float htot = hp;
            #pragma unroll
            for (int gg = 1; gg < 8; ++gg) htot += s_red[t + 64*gg];
            out[(((size_t)b*DOUT + d0)*DOUT + eg)*DOUT + fg] = 1.f / (1.f + __expf(-htot));
        }
    }
}

extern "C" void kernel_launch(void* const* d_in, const int* in_sizes, int n_in,
                              void* d_out, int out_size, void* d_ws, size_t ws_size,
                              hipStream_t stream)
{
    const float* xr = (const float*)d_in[0];
    const float* xi = (const float*)d_in[1];
    const float* wr = (const float*)d_in[2];
    const float* wi = (const float*)d_in[3];
    const float* br = (const float*)d_in[4];
    const float* bi = (const float*)d_in[5];
    const float* hw = (const float*)d_in[6];
    const float* hb = (const float*)d_in[7];
    float* out = (float*)d_out;

    lasl_kernel<<<NBLOCKS, NT, 0, stream>>>(xr, xi, wr, wi, br, bi, hw, hb, out);
}

// Round 9
// 111.437 us; speedup vs baseline: 6.5313x; 1.1366x over previous
//
#include <hip/hip_runtime.h>
#include <math.h>

typedef _Float16 f16x2 __attribute__((ext_vector_type(2)));

namespace {
constexpr int DIN = 36, DOUT = 34;
constexpr int TDD = 2, TE = 8, TF = 8;       // site tile (d,e,f) = (2,8,8) = 128 sites
constexpr int RD = 4, RE = 10, RF = 10;      // staged region rows
constexpr int NROWS = RD*RE*RF;              // 400 rows
constexpr int ROWW  = 37;                    // half2 per row (36+1 pad) = 148 B, ODD dword stride
constexpr int NCHUNK = NROWS*9;              // 3600 16-B source chunks
constexpr int NBD = 17, NBE = 5, NBF = 5;
constexpr int BLOCKS_PER_B = NBD*NBE*NBF;    // 425
constexpr int NBLOCKS = 8*BLOCKS_PER_B;      // 3400 = 8 XCDs x 425
constexpr int NT = 512;
constexpr int SITER = (NCHUNK + NT - 1)/NT;  // 8
}

__device__ __forceinline__ unsigned div9u(unsigned n)   { return __umulhi(n, 0x38E38E39u) >> 1; }
__device__ __forceinline__ unsigned div100u(unsigned n) { return __umulhi(n, 0x51EB851Fu) >> 5; }
__device__ __forceinline__ unsigned div10u(unsigned n)  { return __umulhi(n, 0x66666667u) >> 2; }

__device__ __forceinline__ float h2f(f16x2 h) { union { f16x2 h; float f; } u; u.h = h; return u.f; }
__device__ __forceinline__ f16x2 f2h(float f) { union { float f; f16x2 h; } u; u.f = f; return u.h; }
__device__ __forceinline__ f16x2 u2h(unsigned v) { union { unsigned u; f16x2 h; } u_; u_.u = v; return u_.h; }

#if __has_builtin(__builtin_amdgcn_fdot2)
__device__ __forceinline__ float dot2(f16x2 a, f16x2 b, float c) {
    return __builtin_amdgcn_fdot2(a, b, c, false);
}
#else
__device__ __forceinline__ float dot2(f16x2 a, f16x2 b, float c) {
    return fmaf((float)a.x, (float)b.x, fmaf((float)a.y, (float)b.y, c));
}
#endif

// Coalesced stage of both channels, interleaved (xr,xi) half2 per dword.
// Chunk C: row C/9, 4 floats at chunk C%9. LDS writes are 4x b32 (rows are only
// 4-B aligned by design -- the odd row stride is the bank-conflict fix).
__device__ __forceinline__ void stage(const float* __restrict__ xr, const float* __restrict__ xi,
                                      unsigned* __restrict__ s_xu, int t, int d0, int e0, int f0)
{
    #pragma unroll
    for (int it = 0; it < SITER; ++it) {
        const int C = it*NT + t;
        if (C < NCHUNK) {
            const unsigned row = div9u((unsigned)C);
            const unsigned c   = (unsigned)C - row*9u;
            const unsigned rd  = div100u(row);
            const unsigned rem = row - rd*100u;
            const unsigned re  = div10u(rem);
            const unsigned rf  = rem - re*10u;
            const int ee = min((int)(e0+re), 35);     // clamped tail rows are read
            const int ff = min((int)(f0+rf), 35);     // only by inactive sites
            const size_t goff = (((size_t)(d0+rd)*DIN + ee)*DIN + ff)*DIN + c*4;
            const float4 vr = *reinterpret_cast<const float4*>(xr + goff);
            const float4 vi = *reinterpret_cast<const float4*>(xi + goff);
            unsigned pk[4];
            pk[0] = __builtin_bit_cast(unsigned, f2h(0.f)), // placate -Wunused pattern
            pk[0] = *reinterpret_cast<const unsigned*>(&(const f16x2&)f16x2{(_Float16)vr.x, (_Float16)vi.x});
            pk[1] = *reinterpret_cast<const unsigned*>(&(const f16x2&)f16x2{(_Float16)vr.y, (_Float16)vi.y});
            pk[2] = *reinterpret_cast<const unsigned*>(&(const f16x2&)f16x2{(_Float16)vr.z, (_Float16)vi.z});
            pk[3] = *reinterpret_cast<const unsigned*>(&(const f16x2&)f16x2{(_Float16)vr.w, (_Float16)vi.w});
            unsigned* dst = s_xu + row*ROWW + c*4;
            dst[0] = pk[0]; dst[1] = pk[1]; dst[2] = pk[2]; dst[3] = pk[3];
        }
    }
}

// One w-group's conv + epilogue. All register indices compile-time.
template<int NW, int W0>
__device__ __forceinline__ float conv_group(const unsigned* __restrict__ s_xu,
                                            const float4* __restrict__ s_wA,
                                            const float4* __restrict__ s_wB,
                                            int td, int e, int f,
                                            const float* __restrict__ s_hw,
                                            float c_br, float c_bi, float hinit)
{
    float yr[NW], yi[NW];
    #pragma unroll
    for (int w = 0; w < NW; ++w) { yr[w] = c_br; yi[w] = c_bi; }

    #pragma unroll 1
    for (int i = 0; i < 3; ++i)
    #pragma unroll 1
    for (int j = 0; j < 3; ++j)
    #pragma unroll 1
    for (int k = 0; k < 3; ++k)
    {
        const int r = (td+i)*(RE*RF) + (e+j)*RF + (f+k);
        const unsigned* sp = s_xu + r*ROWW + W0;
        f16x2 win[NW+2];
        #pragma unroll
        for (int m = 0; m < NW+2; ++m) win[m] = u2h(sp[m]);   // b32 reads, odd stride

        const int tap = (i*3 + j)*3 + k;
        const float4 wa = s_wA[tap];                  // uniform broadcast reads
        const float4 wb = s_wB[tap];
        #pragma unroll
        for (int l = 0; l < 3; ++l) {
            const f16x2 wal = f2h(l==0 ? wa.x : l==1 ? wa.y : wa.z);  // (wr, -wi)
            const f16x2 wbl = f2h(l==0 ? wb.x : l==1 ? wb.y : wb.z);  // (wi,  wr)
            #pragma unroll
            for (int w = 0; w < NW; ++w) {
                yr[w] = dot2(win[w+l], wal, yr[w]);
                yi[w] = dot2(win[w+l], wbl, yi[w]);
            }
        }
    }

    float h = hinit;
    #pragma unroll
    for (int w = 0; w < NW; ++w) {
        const float a = fmaxf(yr[w], 0.f);
        const float c = fmaxf(yi[w], 0.f);
        const float m = sqrtf(fmaf(a, a, fmaf(c, c, 1e-12f)));
        h = fmaf(m, s_hw[W0 + w], h);
    }
    return h;
}

__global__ __launch_bounds__(NT)
void lasl_kernel(const float* __restrict__ xr, const float* __restrict__ xi,
                 const float* __restrict__ wr, const float* __restrict__ wi,
                 const float* __restrict__ br, const float* __restrict__ bi,
                 const float* __restrict__ hw, const float* __restrict__ hb,
                 float* __restrict__ out)
{
    __shared__ unsigned s_xu[NROWS*ROWW];           // 59.2 KB, odd-dword row stride
    __shared__ float4 s_wA[27], s_wB[27];
    __shared__ float  s_hw[DOUT], s_scal[3];

    const int t = threadIdx.x;
    if (t < 27) {
        const float w0r = wr[3*t], w1r = wr[3*t+1], w2r = wr[3*t+2];
        const float w0i = wi[3*t], w1i = wi[3*t+1], w2i = wi[3*t+2];
        s_wA[t] = make_float4(h2f(f16x2{(_Float16)w0r, (_Float16)(-w0i)}),
                              h2f(f16x2{(_Float16)w1r, (_Float16)(-w1i)}),
                              h2f(f16x2{(_Float16)w2r, (_Float16)(-w2i)}), 0.f);
        s_wB[t] = make_float4(h2f(f16x2{(_Float16)w0i, (_Float16)w0r}),
                              h2f(f16x2{(_Float16)w1i, (_Float16)w1r}),
                              h2f(f16x2{(_Float16)w2i, (_Float16)w2r}), 0.f);
    } else if (t >= 32 && t < 32 + DOUT) {
        s_hw[t-32] = hw[t-32];
    } else if (t == 96) { s_scal[0] = br[0]; s_scal[1] = bi[0]; s_scal[2] = hb[0]; }

    // batch-per-XCD bijective swizzle: 3400 = 8 * 425
    const int bid = blockIdx.x;
    const int b   = bid & 7;
    int rem = bid >> 3;                              // 0..424
    const int d0 = (rem / 25) * TDD;  rem %= 25;
    const int e0 = (rem / 5) * TE;
    const int f0 = (rem % 5) * TF;

    const size_t bstride = (size_t)DIN*DIN*DIN*DIN;
    stage(xr + (size_t)b*bstride, xi + (size_t)b*bstride, s_xu, t, d0, e0, f0);
    __syncthreads();

    const int f  = t & 7;                            // site within tile
    const int e  = (t >> 3) & 7;
    const int g  = (t >> 6) & 3;                     // wave-uniform w-group (4 groups)
    const int td = t >> 8;                           // wave-uniform d-sub

    const float c_br = s_scal[0], c_bi = s_scal[1];
    const float hini = (g == 0) ? s_scal[2] : 0.f;   // hb counted once

    float hp;
    if      (g == 0) hp = conv_group<9, 0>(s_xu, s_wA, s_wB, td, e, f, s_hw, c_br, c_bi, hini);
    else if (g == 1) hp = conv_group<8, 9>(s_xu, s_wA, s_wB, td, e, f, s_hw, c_br, c_bi, hini);
    else if (g == 2) hp = conv_group<9,17>(s_xu, s_wA, s_wB, td, e, f, s_hw, c_br, c_bi, hini);
    else             hp = conv_group<8,26>(s_xu, s_wA, s_wB, td, e, f, s_hw, c_br, c_bi, hini);

    // combine the 4 w-group partials (one per wave, same td) through LDS
    __syncthreads();                                 // all s_xu reads done
    float* s_red = reinterpret_cast<float*>(s_xu);
    s_red[t] = hp;
    __syncthreads();

    if (g == 0) {
        const int eg = e0 + e, fg = f0 + f;
        if (eg < DOUT && fg < DOUT) {
            const float htot = hp + s_red[t + 64] + s_red[t + 128] + s_red[t + 192];
            out[(((size_t)b*DOUT + (d0 + td))*DOUT + eg)*DOUT + fg] = 1.f / (1.f + __expf(-htot));
        }
    }
}

extern "C" void kernel_launch(void* const* d_in, const int* in_sizes, int n_in,
                              void* d_out, int out_size, void* d_ws, size_t ws_size,
                              hipStream_t stream)
{
    const float* xr = (const float*)d_in[0];
    const float* xi = (const float*)d_in[1];
    const float* wr = (const float*)d_in[2];
    const float* wi = (const float*)d_in[3];
    const float* br = (const float*)d_in[4];
    const float* bi = (const float*)d_in[5];
    const float* hw = (const float*)d_in[6];
    const float* hb = (const float*)d_in[7];
    float* out = (float*)d_out;

    lasl_kernel<<<NBLOCKS, NT, 0, stream>>>(xr, xi, wr, wi, br, bi, hw, hb, out);
}